// Round 1
// baseline (272.965 us; speedup 1.0000x reference)
//
#include <hip/hip_runtime.h>
#include <hip/hip_bf16.h>
#include <cstdint>

// Problem: B=2, S=2048, D=1024, H=16, DK=64. fp32 I/O, bf16 MFMA compute.
#define B_ 2
#define S_ 2048
#define D_ 1024
#define H_ 16
#define DK_ 64

typedef __attribute__((ext_vector_type(8))) short bf16x8;
typedef __attribute__((ext_vector_type(4))) float f32x4;

__device__ __forceinline__ unsigned short f2bf(float f) {
  unsigned u = __float_as_uint(f);
  u = (u + 0x7FFFu + ((u >> 16) & 1u)) >> 16;
  return (unsigned short)u;
}

typedef __attribute__((address_space(1))) void gv_t;
typedef __attribute__((address_space(3))) void lv_t;
__device__ __forceinline__ void gl16(const void* g, void* l) {
  // async global->LDS, 16B per lane; LDS dest = wave-uniform base + lane*16
  __builtin_amdgcn_global_load_lds((gv_t*)g, (lv_t*)l, 16, 0, 0);
}

// ---------------- fp32 -> bf16 convert ----------------
__global__ void cvt_kernel(const float* __restrict__ in, unsigned short* __restrict__ out, int n4) {
  int i = blockIdx.x * blockDim.x + threadIdx.x;
  if (i >= n4) return;
  const float4 v = reinterpret_cast<const float4*>(in)[i];
  ushort4 o;
  o.x = f2bf(v.x); o.y = f2bf(v.y); o.z = f2bf(v.z); o.w = f2bf(v.w);
  reinterpret_cast<ushort4*>(out)[i] = o;
}

// ---------------- GEMM: C = A * B^T  (A:[M,K], B:[N,K] both row-major bf16) ----------------
// Fused over up to 3 weight matrices selected by blockIdx.x / (N/BN).
#define BM 128
#define BN 128
#define BK 64

template <typename OutT>
__global__ __launch_bounds__(256) void gemm_bt(
    const unsigned short* __restrict__ A,
    const unsigned short* __restrict__ B0, const unsigned short* __restrict__ B1,
    const unsigned short* __restrict__ B2,
    OutT* __restrict__ C0, OutT* __restrict__ C1, OutT* __restrict__ C2,
    int M, int N, int K) {
  __shared__ unsigned short lA[BM * BK];
  __shared__ unsigned short lB[BN * BK];
  const int tid = threadIdx.x;
  const int wave = tid >> 6, lane = tid & 63;
  const int l16 = lane & 15, lq = lane >> 4;
  const int wr = wave >> 1, wc = wave & 1;

  const int tilesPerMat = N / BN;
  const int bx = blockIdx.x;
  const int mat = bx / tilesPerMat;
  const int n0 = (bx % tilesPerMat) * BN;
  const unsigned short* Bm = (mat == 0) ? B0 : (mat == 1) ? B1 : B2;
  OutT* C = (mat == 0) ? C0 : (mat == 1) ? C1 : C2;
  const int m0 = blockIdx.y * BM;

  f32x4 acc[4][4] = {};

  for (int k0 = 0; k0 < K; k0 += BK) {
    __syncthreads();
#pragma unroll
    for (int q = 0; q < 4; ++q) {
      int c = q * 4 + wave;               // chunk 0..15, 8 rows each
      int row = c * 8 + (lane >> 3);
      int col = (lane & 7) * 8;
      gl16(A + (size_t)(m0 + row) * K + k0 + col, &lA[c * 512]);
      gl16(Bm + (size_t)(n0 + row) * K + k0 + col, &lB[c * 512]);
    }
    __syncthreads();
#pragma unroll
    for (int kk = 0; kk < BK / 32; ++kk) {
      bf16x8 af[4], bfr[4];
#pragma unroll
      for (int m = 0; m < 4; ++m)
        af[m] = *(const bf16x8*)&lA[(wr * 64 + m * 16 + l16) * BK + kk * 32 + lq * 8];
#pragma unroll
      for (int n = 0; n < 4; ++n)
        bfr[n] = *(const bf16x8*)&lB[(wc * 64 + n * 16 + l16) * BK + kk * 32 + lq * 8];
#pragma unroll
      for (int m = 0; m < 4; ++m)
#pragma unroll
        for (int n = 0; n < 4; ++n)
          acc[m][n] = __builtin_amdgcn_mfma_f32_16x16x32_bf16(af[m], bfr[n], acc[m][n], 0, 0, 0);
    }
  }

#pragma unroll
  for (int m = 0; m < 4; ++m)
#pragma unroll
    for (int n = 0; n < 4; ++n)
#pragma unroll
      for (int j = 0; j < 4; ++j) {
        int r = m0 + wr * 64 + m * 16 + lq * 4 + j;   // row = (lane>>4)*4 + reg
        int cidx = n0 + wc * 64 + n * 16 + l16;        // col = lane&15
        float v = acc[m][n][j];
        if constexpr (sizeof(OutT) == 4) C[(size_t)r * N + cidx] = v;
        else C[(size_t)r * N + cidx] = f2bf(v);
      }
}

// ---------------- flash attention (causal) ----------------
// grid: (S/64, H, B); block: 256 (4 waves, 16 q-rows each). K/V tiles of 64.
__global__ __launch_bounds__(256) void attn_kernel(
    const unsigned short* __restrict__ Qg, const unsigned short* __restrict__ Kg,
    const unsigned short* __restrict__ Vg, unsigned short* __restrict__ Og) {
  __shared__ unsigned short sQ[64 * 64];
  __shared__ unsigned short sK[64 * 64];
  __shared__ unsigned short sVt[64 * 64];      // transposed: [dv][kv]
  __shared__ unsigned short sP[4][16 * 64];    // per-wave P tile
  const int tid = threadIdx.x, wave = tid >> 6, lane = tid & 63;
  const int l16 = lane & 15, lq = lane >> 4;
  const int qt = blockIdx.x, h = blockIdx.y, b = blockIdx.z;
  const int q0 = qt * 64;
  const size_t base = (size_t)b * S_ * D_ + h * DK_;

  // stage Q tile [64 rows][64 dk]
#pragma unroll
  for (int qq = 0; qq < 4; ++qq) {
    int c = qq * 4 + wave;
    int row = c * 8 + (lane >> 3);
    int col = (lane & 7) * 8;
    gl16(Qg + base + (size_t)(q0 + row) * D_ + col, &sQ[c * 512]);
  }
  __syncthreads();
  bf16x8 aq[2];
  aq[0] = *(const bf16x8*)&sQ[(wave * 16 + l16) * 64 + 0 + lq * 8];
  aq[1] = *(const bf16x8*)&sQ[(wave * 16 + l16) * 64 + 32 + lq * 8];

  float m_run[4] = {-1e30f, -1e30f, -1e30f, -1e30f};
  float l_run[4] = {0.f, 0.f, 0.f, 0.f};
  f32x4 o_acc[4] = {};

  const int vkv = tid >> 2;   // V-transpose role: kv row 0..63
  const int vg = tid & 3;     // dv group of 16

  for (int kt = 0; kt <= qt; ++kt) {
    __syncthreads();
    // stage K tile
#pragma unroll
    for (int qq = 0; qq < 4; ++qq) {
      int c = qq * 4 + wave;
      int row = c * 8 + (lane >> 3);
      int col = (lane & 7) * 8;
      gl16(Kg + base + (size_t)(kt * 64 + row) * D_ + col, &sK[c * 512]);
    }
    // stage V transposed (scalar LDS writes)
    {
      union { uint4 u[2]; unsigned short us[16]; } t;
      const unsigned short* vp = Vg + base + (size_t)(kt * 64 + vkv) * D_ + vg * 16;
      t.u[0] = *(const uint4*)(vp);
      t.u[1] = *(const uint4*)(vp + 8);
#pragma unroll
      for (int i = 0; i < 16; ++i) sVt[(vg * 16 + i) * 64 + vkv] = t.us[i];
    }
    __syncthreads();

    // QK^T: S[16 q][64 k]
    f32x4 sc[4];
#pragma unroll
    for (int nb = 0; nb < 4; ++nb) {
      bf16x8 bk0 = *(const bf16x8*)&sK[(nb * 16 + l16) * 64 + 0 + lq * 8];
      bf16x8 bk1 = *(const bf16x8*)&sK[(nb * 16 + l16) * 64 + 32 + lq * 8];
      f32x4 a = {};
      a = __builtin_amdgcn_mfma_f32_16x16x32_bf16(aq[0], bk0, a, 0, 0, 0);
      a = __builtin_amdgcn_mfma_f32_16x16x32_bf16(aq[1], bk1, a, 0, 0, 0);
      sc[nb] = a;
    }

    // scale + causal mask + online softmax
    float p[4][4];
#pragma unroll
    for (int nb = 0; nb < 4; ++nb)
#pragma unroll
      for (int j = 0; j < 4; ++j) {
        float v = sc[nb][j] * 0.125f;
        int kidx = kt * 64 + nb * 16 + l16;
        int qidx = q0 + wave * 16 + lq * 4 + j;
        if (kidx > qidx) v = -1e30f;
        p[nb][j] = v;
      }
#pragma unroll
    for (int j = 0; j < 4; ++j) {
      float rmax = fmaxf(fmaxf(p[0][j], p[1][j]), fmaxf(p[2][j], p[3][j]));
#pragma unroll
      for (int d = 1; d < 16; d <<= 1) rmax = fmaxf(rmax, __shfl_xor(rmax, d));
      float mn = fmaxf(m_run[j], rmax);
      float alpha = __expf(m_run[j] - mn);
      m_run[j] = mn;
      float ps = 0.f;
#pragma unroll
      for (int nb = 0; nb < 4; ++nb) {
        float e = __expf(p[nb][j] - mn);
        ps += e;
        sP[wave][(lq * 4 + j) * 64 + nb * 16 + l16] = f2bf(e);
      }
#pragma unroll
      for (int d = 1; d < 16; d <<= 1) ps += __shfl_xor(ps, d);
      l_run[j] = l_run[j] * alpha + ps;
#pragma unroll
      for (int nb = 0; nb < 4; ++nb) o_acc[nb][j] *= alpha;
    }
    __syncthreads();   // sP visible (and keeps waves in lockstep for next staging)

    // PV: O[16 q][64 dv] += P[16 q][64 kv] * V[64 kv][64 dv]
#pragma unroll
    for (int kk = 0; kk < 2; ++kk) {
      bf16x8 ap = *(const bf16x8*)&sP[wave][l16 * 64 + kk * 32 + lq * 8];
#pragma unroll
      for (int nb = 0; nb < 4; ++nb) {
        bf16x8 bv = *(const bf16x8*)&sVt[(nb * 16 + l16) * 64 + kk * 32 + lq * 8];
        o_acc[nb] = __builtin_amdgcn_mfma_f32_16x16x32_bf16(ap, bv, o_acc[nb], 0, 0, 0);
      }
    }
  }

  // normalize + store bf16
#pragma unroll
  for (int j = 0; j < 4; ++j) {
    float inv = 1.f / l_run[j];
#pragma unroll
    for (int nb = 0; nb < 4; ++nb) {
      int r = q0 + wave * 16 + lq * 4 + j;
      Og[base + (size_t)r * D_ + nb * 16 + l16] = f2bf(o_acc[nb][j] * inv);
    }
  }
}

// ---------------- launch ----------------
extern "C" void kernel_launch(void* const* d_in, const int* in_sizes, int n_in,
                              void* d_out, int out_size, void* d_ws, size_t ws_size,
                              hipStream_t stream) {
  const float* x = (const float*)d_in[0];
  const float* wq = (const float*)d_in[1];
  const float* wk = (const float*)d_in[2];
  const float* wv = (const float*)d_in[3];
  const float* wo = (const float*)d_in[4];
  float* out = (float*)d_out;

  char* ws = (char*)d_ws;
  const size_t MB = 1024 * 1024;
  unsigned short* xb  = (unsigned short*)(ws + 0);        // 4096x1024 bf16 (8MB)
  unsigned short* wqb = (unsigned short*)(ws + 8 * MB);   // 2MB each
  unsigned short* wkb = (unsigned short*)(ws + 10 * MB);
  unsigned short* wvb = (unsigned short*)(ws + 12 * MB);
  unsigned short* wob = (unsigned short*)(ws + 14 * MB);
  unsigned short* Qb  = (unsigned short*)(ws + 16 * MB);  // 8MB each
  unsigned short* Kb  = (unsigned short*)(ws + 24 * MB);
  unsigned short* Vb  = (unsigned short*)(ws + 32 * MB);
  unsigned short* AOb = (unsigned short*)(ws + 40 * MB);  // attn output, 8MB

  const int M = B_ * S_;        // 4096
  const int N = D_, K = D_;     // 1024

  // fp32 -> bf16
  cvt_kernel<<<dim3((M * D_ / 4 + 255) / 256), 256, 0, stream>>>(x, xb, M * D_ / 4);
  cvt_kernel<<<dim3((D_ * D_ / 4 + 255) / 256), 256, 0, stream>>>(wq, wqb, D_ * D_ / 4);
  cvt_kernel<<<dim3((D_ * D_ / 4 + 255) / 256), 256, 0, stream>>>(wk, wkb, D_ * D_ / 4);
  cvt_kernel<<<dim3((D_ * D_ / 4 + 255) / 256), 256, 0, stream>>>(wv, wvb, D_ * D_ / 4);
  cvt_kernel<<<dim3((D_ * D_ / 4 + 255) / 256), 256, 0, stream>>>(wo, wob, D_ * D_ / 4);

  // fused QKV projection: grid.x = 3 matrices * 8 n-tiles
  gemm_bt<unsigned short><<<dim3(3 * (N / BN), M / BM), 256, 0, stream>>>(
      xb, wqb, wkb, wvb, Qb, Kb, Vb, M, N, K);

  // causal flash attention
  attn_kernel<<<dim3(S_ / 64, H_, B_), 256, 0, stream>>>(Qb, Kb, Vb, AOb);

  // output projection -> fp32 d_out
  gemm_bt<float><<<dim3(N / BN, M / BM), 256, 0, stream>>>(
      AOb, wob, wob, wob, out, out, out, M, N, K);
}

// Round 2
// 156.148 us; speedup vs baseline: 1.7481x; 1.7481x over previous
//
#include <hip/hip_runtime.h>
#include <hip/hip_bf16.h>
#include <cstdint>

// Problem: B=2, S=2048, D=1024, H=16, DK=64. fp32 I/O, bf16 MFMA compute.
#define B_ 2
#define S_ 2048
#define D_ 1024
#define H_ 16
#define DK_ 64

typedef __attribute__((ext_vector_type(8))) short bf16x8;
typedef __attribute__((ext_vector_type(4))) float f32x4;

__device__ __forceinline__ unsigned short f2bf(float f) {
  unsigned u = __float_as_uint(f);
  u = (u + 0x7FFFu + ((u >> 16) & 1u)) >> 16;
  return (unsigned short)u;
}

typedef __attribute__((address_space(1))) void gv_t;
typedef __attribute__((address_space(3))) void lv_t;
__device__ __forceinline__ void gl16(const void* g, void* l) {
  // async global->LDS, 16B per lane; LDS dest = wave-uniform base + lane*16
  __builtin_amdgcn_global_load_lds((gv_t*)g, (lv_t*)l, 16, 0, 0);
}

// Stage a 64-row x 64-col bf16 tile into LDS (linear dest), with the global
// source pre-swizzled so that LDS slot (row, g16) holds global group g16^(row&7).
// (T21: linear gl16 dest + inverse-swizzled source + swizzled reads.)
__device__ __forceinline__ void stage64x64_swz(const unsigned short* gbase, size_t ldg,
                                               unsigned short* lds, int wave, int lane) {
  const int lr = lane >> 3;
  const int col8 = (lane & 7) ^ lr;   // inverse-swizzled 8-elem group to fetch
#pragma unroll
  for (int q = 0; q < 4; ++q) {
    int c = q * 4 + wave;             // chunk of 8 rows
    int row = c * 8 + lr;
    gl16(gbase + (size_t)row * ldg + col8 * 8, lds + c * 512);
  }
}

// Swizzled bf16x8 fragment read from a [rows][64] tile staged by stage64x64_swz.
__device__ __forceinline__ bf16x8 rdswz(const unsigned short* lds, int row, int colelem) {
  return *(const bf16x8*)&lds[row * 64 + (colelem ^ ((row & 7) << 3))];
}

// ---------------- fp32 -> bf16 convert ----------------
__global__ void cvt_kernel(const float* __restrict__ in, unsigned short* __restrict__ out, int n4) {
  int i = blockIdx.x * blockDim.x + threadIdx.x;
  if (i >= n4) return;
  const float4 v = reinterpret_cast<const float4*>(in)[i];
  ushort4 o;
  o.x = f2bf(v.x); o.y = f2bf(v.y); o.z = f2bf(v.z); o.w = f2bf(v.w);
  reinterpret_cast<ushort4*>(out)[i] = o;
}

// ---------------- V transpose: V[b*S+s][h*64+dv] -> Vt[((b*H+h)*64+dv)*S + s] ----------------
__global__ __launch_bounds__(256) void vtrans_kernel(const unsigned short* __restrict__ V,
                                                     unsigned short* __restrict__ Vt) {
  __shared__ unsigned short t[64][72];
  const int s0 = blockIdx.x * 64, h = blockIdx.y, b = blockIdx.z;
  const int tid = threadIdx.x;
  {
    int r = tid >> 2, cs = tid & 3;
    const unsigned short* src = V + ((size_t)(b * S_ + s0 + r)) * D_ + h * DK_ + cs * 16;
    *(bf16x8*)&t[r][cs * 16] = *(const bf16x8*)src;
    *(bf16x8*)&t[r][cs * 16 + 8] = *(const bf16x8*)(src + 8);
  }
  __syncthreads();
  {
    int dv = tid >> 2, ks = tid & 3;
    unsigned short tmp[16];
#pragma unroll
    for (int k = 0; k < 16; ++k) tmp[k] = t[ks * 16 + k][dv];
    unsigned short* dst = Vt + ((size_t)(b * H_ + h) * DK_ + dv) * S_ + s0 + ks * 16;
    *(bf16x8*)dst = *(const bf16x8*)&tmp[0];
    *(bf16x8*)(dst + 8) = *(const bf16x8*)&tmp[8];
  }
}

// ---------------- GEMM: C = A * B^T  (A:[M,K], B:[N,K] both row-major bf16) ----------------
#define BM 128
#define BN 128
#define BK 64

template <typename OutT>
__global__ __launch_bounds__(256) void gemm_bt(
    const unsigned short* __restrict__ A,
    const unsigned short* __restrict__ B0, const unsigned short* __restrict__ B1,
    const unsigned short* __restrict__ B2,
    OutT* __restrict__ C0, OutT* __restrict__ C1, OutT* __restrict__ C2,
    int M, int N, int K) {
  __shared__ unsigned short lA[BM * BK];
  __shared__ unsigned short lB[BN * BK];
  const int tid = threadIdx.x;
  const int wave = tid >> 6, lane = tid & 63;
  const int l16 = lane & 15, lqq = lane >> 4;
  const int wr = wave >> 1, wc = wave & 1;
  const int lr = lane >> 3;
  const int col8 = ((lane & 7) ^ lr) * 8;   // inverse-swizzled source group

  const int tilesPerMat = N / BN;
  const int bx = blockIdx.x;
  const int mat = bx / tilesPerMat;
  const int n0 = (bx % tilesPerMat) * BN;
  const unsigned short* Bm = (mat == 0) ? B0 : (mat == 1) ? B1 : B2;
  OutT* C = (mat == 0) ? C0 : (mat == 1) ? C1 : C2;
  const int m0 = blockIdx.y * BM;

  f32x4 acc[4][4] = {};

  for (int k0 = 0; k0 < K; k0 += BK) {
    __syncthreads();
#pragma unroll
    for (int q = 0; q < 4; ++q) {
      int c = q * 4 + wave;               // chunk 0..15, 8 rows each
      int row = c * 8 + lr;
      gl16(A + (size_t)(m0 + row) * K + k0 + col8, &lA[c * 512]);
      gl16(Bm + (size_t)(n0 + row) * K + k0 + col8, &lB[c * 512]);
    }
    __syncthreads();
#pragma unroll
    for (int kk = 0; kk < BK / 32; ++kk) {
      bf16x8 af[4], bfr[4];
#pragma unroll
      for (int m = 0; m < 4; ++m)
        af[m] = rdswz(lA, wr * 64 + m * 16 + l16, kk * 32 + lqq * 8);
#pragma unroll
      for (int n = 0; n < 4; ++n)
        bfr[n] = rdswz(lB, wc * 64 + n * 16 + l16, kk * 32 + lqq * 8);
#pragma unroll
      for (int m = 0; m < 4; ++m)
#pragma unroll
        for (int n = 0; n < 4; ++n)
          acc[m][n] = __builtin_amdgcn_mfma_f32_16x16x32_bf16(af[m], bfr[n], acc[m][n], 0, 0, 0);
    }
  }

#pragma unroll
  for (int m = 0; m < 4; ++m)
#pragma unroll
    for (int n = 0; n < 4; ++n)
#pragma unroll
      for (int j = 0; j < 4; ++j) {
        int r = m0 + wr * 64 + m * 16 + lqq * 4 + j;   // row = (lane>>4)*4 + reg
        int cidx = n0 + wc * 64 + n * 16 + l16;        // col = lane&15
        float v = acc[m][n][j];
        if constexpr (sizeof(OutT) == 4) C[(size_t)r * N + cidx] = v;
        else C[(size_t)r * N + cidx] = f2bf(v);
      }
}

// ---------------- flash attention (causal) ----------------
// grid: 512 blocks; each block handles q-tile pair {qp, 31-qp} for one (b,h)
// -> constant 33 KV-tiles of work per block. Block-id mapping co-locates all
// blocks of one (b,h) on one XCD (ids stride 32 => same id%8).
__global__ __launch_bounds__(256) void attn_kernel(
    const unsigned short* __restrict__ Qg, const unsigned short* __restrict__ Kg,
    const unsigned short* __restrict__ Vtg, unsigned short* __restrict__ Og) {
  __shared__ unsigned short sQ[64 * 64];
  __shared__ unsigned short sK[64 * 64];
  __shared__ unsigned short sVt[64 * 64];      // transposed tile: [dv][kv], swizzled
  __shared__ unsigned short sP[4][16 * 64];    // per-wave P tile, swizzled
  const int tid = threadIdx.x, wave = tid >> 6, lane = tid & 63;
  const int l16 = lane & 15, lq = lane >> 4;
  const int id = blockIdx.x;
  const int bh = (id & 7) * 4 + ((id >> 3) & 3);   // XCD-grouped (b,h)
  const int qpair = id >> 5;                        // 0..15
  const int b = bh >> 4, h = bh & 15;
  const size_t tokbase = (size_t)b * S_ * D_ + h * DK_;
  const unsigned short* VtB = Vtg + (size_t)(b * H_ + h) * DK_ * S_;
  unsigned short* sPw = sP[wave];

#pragma unroll 1
  for (int side = 0; side < 2; ++side) {
    const int qt = side ? (31 - qpair) : qpair;
    const int q0 = qt * 64;

    __syncthreads();
    stage64x64_swz(Qg + tokbase + (size_t)q0 * D_, D_, sQ, wave, lane);
    __syncthreads();
    bf16x8 aq0 = rdswz(sQ, wave * 16 + l16, 0 + lq * 8);
    bf16x8 aq1 = rdswz(sQ, wave * 16 + l16, 32 + lq * 8);

    float m_run[4] = {-1e30f, -1e30f, -1e30f, -1e30f};
    float l_run[4] = {0.f, 0.f, 0.f, 0.f};
    f32x4 o_acc[4] = {};

#pragma unroll 1
    for (int kt = 0; kt <= qt; ++kt) {
      __syncthreads();   // (A) prior iteration's reads of sK/sVt complete
      stage64x64_swz(Kg + tokbase + (size_t)(kt * 64) * D_, D_, sK, wave, lane);
      stage64x64_swz(VtB + kt * 64, S_, sVt, wave, lane);
      __syncthreads();   // (B) staging drained (compiler emits vmcnt(0) before barrier)

      // QK^T: S[16 q][64 k]
      f32x4 sc[4];
#pragma unroll
      for (int nb = 0; nb < 4; ++nb) {
        bf16x8 bk0 = rdswz(sK, nb * 16 + l16, 0 + lq * 8);
        bf16x8 bk1 = rdswz(sK, nb * 16 + l16, 32 + lq * 8);
        f32x4 a = {};
        a = __builtin_amdgcn_mfma_f32_16x16x32_bf16(aq0, bk0, a, 0, 0, 0);
        a = __builtin_amdgcn_mfma_f32_16x16x32_bf16(aq1, bk1, a, 0, 0, 0);
        sc[nb] = a;
      }

      // scale + causal mask (only the diagonal tile needs it) + online softmax
      float p[4][4];
#pragma unroll
      for (int nb = 0; nb < 4; ++nb)
#pragma unroll
        for (int j = 0; j < 4; ++j) p[nb][j] = sc[nb][j] * 0.125f;
      if (kt == qt) {
#pragma unroll
        for (int nb = 0; nb < 4; ++nb)
#pragma unroll
          for (int j = 0; j < 4; ++j) {
            int kidx = nb * 16 + l16;
            int qidx = wave * 16 + lq * 4 + j;
            if (kidx > qidx) p[nb][j] = -1e30f;
          }
      }
#pragma unroll
      for (int j = 0; j < 4; ++j) {
        float rmax = fmaxf(fmaxf(p[0][j], p[1][j]), fmaxf(p[2][j], p[3][j]));
#pragma unroll
        for (int d = 1; d < 16; d <<= 1) rmax = fmaxf(rmax, __shfl_xor(rmax, d));
        float mn = fmaxf(m_run[j], rmax);
        float alpha = __expf(m_run[j] - mn);
        m_run[j] = mn;
        const int rw = lq * 4 + j;
        float ps = 0.f;
#pragma unroll
        for (int nb = 0; nb < 4; ++nb) {
          float e = __expf(p[nb][j] - mn);
          ps += e;
          sPw[rw * 64 + ((nb * 16 + l16) ^ ((rw & 7) << 3))] = f2bf(e);
        }
#pragma unroll
        for (int d = 1; d < 16; d <<= 1) ps += __shfl_xor(ps, d);
        l_run[j] = l_run[j] * alpha + ps;
#pragma unroll
        for (int nb = 0; nb < 4; ++nb) o_acc[nb][j] *= alpha;
      }

      // PV: O[16 q][64 dv] += P[16 q][64 kv] * Vt[64 dv][64 kv]^T
      // sP is per-wave private: no barrier needed (compiler inserts lgkmcnt waits).
#pragma unroll
      for (int kk = 0; kk < 2; ++kk) {
        bf16x8 ap = rdswz(sPw, l16, kk * 32 + lq * 8);
#pragma unroll
        for (int nb = 0; nb < 4; ++nb) {
          bf16x8 bv = rdswz(sVt, nb * 16 + l16, kk * 32 + lq * 8);
          o_acc[nb] = __builtin_amdgcn_mfma_f32_16x16x32_bf16(ap, bv, o_acc[nb], 0, 0, 0);
        }
      }
    }

    // normalize + store bf16
#pragma unroll
    for (int j = 0; j < 4; ++j) {
      float inv = 1.f / l_run[j];
#pragma unroll
      for (int nb = 0; nb < 4; ++nb) {
        int r = q0 + wave * 16 + lq * 4 + j;
        Og[tokbase + (size_t)r * D_ + nb * 16 + l16] = f2bf(o_acc[nb][j] * inv);
      }
    }
  }
}

// ---------------- launch ----------------
extern "C" void kernel_launch(void* const* d_in, const int* in_sizes, int n_in,
                              void* d_out, int out_size, void* d_ws, size_t ws_size,
                              hipStream_t stream) {
  const float* x = (const float*)d_in[0];
  const float* wq = (const float*)d_in[1];
  const float* wk = (const float*)d_in[2];
  const float* wv = (const float*)d_in[3];
  const float* wo = (const float*)d_in[4];
  float* out = (float*)d_out;

  char* ws = (char*)d_ws;
  const size_t MB = 1024 * 1024;
  unsigned short* xb  = (unsigned short*)(ws + 0);        // x bf16 (8MB); dead after QKV GEMM
  unsigned short* wqb = (unsigned short*)(ws + 8 * MB);   // 2MB each
  unsigned short* wkb = (unsigned short*)(ws + 10 * MB);
  unsigned short* wvb = (unsigned short*)(ws + 12 * MB);
  unsigned short* wob = (unsigned short*)(ws + 14 * MB);
  unsigned short* Qb  = (unsigned short*)(ws + 16 * MB);  // 8MB each
  unsigned short* Kb  = (unsigned short*)(ws + 24 * MB);
  unsigned short* Vb  = (unsigned short*)(ws + 32 * MB);
  unsigned short* AOb = (unsigned short*)(ws + 40 * MB);  // attn output, 8MB
  unsigned short* Vtb = xb;                               // reuse xb region for V^T

  const int M = B_ * S_;        // 4096
  const int N = D_, K = D_;     // 1024

  // fp32 -> bf16
  cvt_kernel<<<dim3((M * D_ / 4 + 255) / 256), 256, 0, stream>>>(x, xb, M * D_ / 4);
  cvt_kernel<<<dim3((D_ * D_ / 4 + 255) / 256), 256, 0, stream>>>(wq, wqb, D_ * D_ / 4);
  cvt_kernel<<<dim3((D_ * D_ / 4 + 255) / 256), 256, 0, stream>>>(wk, wkb, D_ * D_ / 4);
  cvt_kernel<<<dim3((D_ * D_ / 4 + 255) / 256), 256, 0, stream>>>(wv, wvb, D_ * D_ / 4);
  cvt_kernel<<<dim3((D_ * D_ / 4 + 255) / 256), 256, 0, stream>>>(wo, wob, D_ * D_ / 4);

  // fused QKV projection: grid.x = 3 matrices * 8 n-tiles
  gemm_bt<unsigned short><<<dim3(3 * (N / BN), M / BM), 256, 0, stream>>>(
      xb, wqb, wkb, wvb, Qb, Kb, Vb, M, N, K);

  // pre-transpose V -> Vt[b][h][dv][s]  (xb region is dead now)
  vtrans_kernel<<<dim3(S_ / 64, H_, B_), 256, 0, stream>>>(Vb, Vtb);

  // causal flash attention (paired q-tiles, XCD-grouped)
  attn_kernel<<<dim3(512), 256, 0, stream>>>(Qb, Kb, Vtb, AOb);

  // output projection -> fp32 d_out
  gemm_bt<float><<<dim3(N / BN, M / BM), 256, 0, stream>>>(
      AOb, wob, wob, wob, out, out, out, M, N, K);
}

// Round 5
// 152.777 us; speedup vs baseline: 1.7867x; 1.0221x over previous
//
#include <hip/hip_runtime.h>
#include <hip/hip_bf16.h>
#include <cstdint>

// Problem: B=2, S=2048, D=1024, H=16, DK=64. fp32 I/O, bf16 MFMA compute.
#define B_ 2
#define S_ 2048
#define D_ 1024
#define H_ 16
#define DK_ 64

typedef __attribute__((ext_vector_type(8))) short bf16x8;
typedef __attribute__((ext_vector_type(4))) float f32x4;

__device__ __forceinline__ unsigned short f2bf(float f) {
  unsigned u = __float_as_uint(f);
  u = (u + 0x7FFFu + ((u >> 16) & 1u)) >> 16;
  return (unsigned short)u;
}

typedef __attribute__((address_space(1))) void gv_t;
typedef __attribute__((address_space(3))) void lv_t;
__device__ __forceinline__ void gl16(const void* g, void* l) {
  __builtin_amdgcn_global_load_lds((gv_t*)g, (lv_t*)l, 16, 0, 0);
}

// Stage a 64x64 bf16 tile into LDS (linear dest) with inverse-swizzled global
// source: LDS slot (row, g16) holds global group g16 ^ (row&7).  (T21)
__device__ __forceinline__ void stage64x64_swz(const unsigned short* gbase, size_t ldg,
                                               unsigned short* lds, int wave, int lane) {
  const int lr = lane >> 3;
  const int col8 = (lane & 7) ^ lr;
#pragma unroll
  for (int q = 0; q < 4; ++q) {
    int c = q * 4 + wave;
    int row = c * 8 + lr;
    gl16(gbase + (size_t)row * ldg + col8 * 8, lds + c * 512);
  }
}

__device__ __forceinline__ bf16x8 rdswz(const unsigned short* lds, int row, int colelem) {
  return *(const bf16x8*)&lds[row * 64 + (colelem ^ ((row & 7) << 3))];
}

// ---------------- fp32 -> bf16 converts ----------------
__global__ void cvt_kernel(const float* __restrict__ in, unsigned short* __restrict__ out, int n4) {
  int i = blockIdx.x * blockDim.x + threadIdx.x;
  if (i >= n4) return;
  const float4 v = reinterpret_cast<const float4*>(in)[i];
  ushort4 o;
  o.x = f2bf(v.x); o.y = f2bf(v.y); o.z = f2bf(v.z); o.w = f2bf(v.w);
  reinterpret_cast<ushort4*>(out)[i] = o;
}

__global__ void cvtw_kernel(const float* __restrict__ w0, const float* __restrict__ w1,
                            const float* __restrict__ w2, const float* __restrict__ w3,
                            unsigned short* __restrict__ o0, unsigned short* __restrict__ o1,
                            unsigned short* __restrict__ o2, unsigned short* __restrict__ o3) {
  const int mat = blockIdx.y;
  const float* in = (mat == 0) ? w0 : (mat == 1) ? w1 : (mat == 2) ? w2 : w3;
  unsigned short* out = (mat == 0) ? o0 : (mat == 1) ? o1 : (mat == 2) ? o2 : o3;
  int i = blockIdx.x * blockDim.x + threadIdx.x;
  const float4 v = reinterpret_cast<const float4*>(in)[i];
  ushort4 o;
  o.x = f2bf(v.x); o.y = f2bf(v.y); o.z = f2bf(v.z); o.w = f2bf(v.w);
  reinterpret_cast<ushort4*>(out)[i] = o;
}

// ---------------- GEMM: C = A * B^T ----------------
// TV2: matrix index 2 writes its output TRANSPOSED into Vt[((b*H+h)*DK+dv)*S+s]
// (fused V-transpose; eliminates the separate vtrans kernel).
#define BM 128
#define BN 128
#define BK 64

template <typename OutT, bool TV2>
__global__ __launch_bounds__(256) void gemm_bt(
    const unsigned short* __restrict__ A,
    const unsigned short* __restrict__ B0, const unsigned short* __restrict__ B1,
    const unsigned short* __restrict__ B2,
    OutT* __restrict__ C0, OutT* __restrict__ C1, OutT* __restrict__ C2,
    int M, int N, int K) {
  __shared__ unsigned short lA[BM * BK];
  __shared__ unsigned short lB[BN * BK];
  const int tid = threadIdx.x;
  const int wave = tid >> 6, lane = tid & 63;
  const int l16 = lane & 15, lqq = lane >> 4;
  const int wr = wave >> 1, wc = wave & 1;
  const int lr = lane >> 3;
  const int col8 = ((lane & 7) ^ lr) * 8;

  const int tilesPerMat = N / BN;
  const int bx = blockIdx.x;
  const int mat = bx / tilesPerMat;
  const int n0 = (bx % tilesPerMat) * BN;
  const unsigned short* Bm = (mat == 0) ? B0 : (mat == 1) ? B1 : B2;
  OutT* C = (mat == 0) ? C0 : (mat == 1) ? C1 : C2;
  const int m0 = blockIdx.y * BM;

  f32x4 acc[4][4] = {};

  for (int k0 = 0; k0 < K; k0 += BK) {
    __syncthreads();
#pragma unroll
    for (int q = 0; q < 4; ++q) {
      int c = q * 4 + wave;
      int row = c * 8 + lr;
      gl16(A + (size_t)(m0 + row) * K + k0 + col8, &lA[c * 512]);
      gl16(Bm + (size_t)(n0 + row) * K + k0 + col8, &lB[c * 512]);
    }
    __syncthreads();
#pragma unroll
    for (int kk = 0; kk < BK / 32; ++kk) {
      bf16x8 af[4], bfr[4];
#pragma unroll
      for (int m = 0; m < 4; ++m)
        af[m] = rdswz(lA, wr * 64 + m * 16 + l16, kk * 32 + lqq * 8);
#pragma unroll
      for (int n = 0; n < 4; ++n)
        bfr[n] = rdswz(lB, wc * 64 + n * 16 + l16, kk * 32 + lqq * 8);
      __builtin_amdgcn_s_setprio(1);
#pragma unroll
      for (int m = 0; m < 4; ++m)
#pragma unroll
        for (int n = 0; n < 4; ++n)
          acc[m][n] = __builtin_amdgcn_mfma_f32_16x16x32_bf16(af[m], bfr[n], acc[m][n], 0, 0, 0);
      __builtin_amdgcn_s_setprio(0);
    }
  }

  if (TV2 && mat == 2) {
    // transposed V write: C row r = token (b = r>>11, s = r&2047),
    // col cidx = h*64+dv.  j=0..3 are contiguous in s (4-aligned, never
    // straddles the b boundary since 2048 % 4 == 0).
    unsigned short* Vt = (unsigned short*)C;
#pragma unroll
    for (int m = 0; m < 4; ++m)
#pragma unroll
      for (int n = 0; n < 4; ++n) {
        int r0 = m0 + wr * 64 + m * 16 + lqq * 4;
        int cidx = n0 + wc * 64 + n * 16 + l16;
        int bb = r0 >> 11, s = r0 & 2047;
        int h = cidx >> 6, dv = cidx & 63;
        ushort4 o;
        o.x = f2bf(acc[m][n][0]); o.y = f2bf(acc[m][n][1]);
        o.z = f2bf(acc[m][n][2]); o.w = f2bf(acc[m][n][3]);
        *(ushort4*)(Vt + ((size_t)((bb * H_ + h) * DK_ + dv)) * S_ + s) = o;
      }
  } else {
#pragma unroll
    for (int m = 0; m < 4; ++m)
#pragma unroll
      for (int n = 0; n < 4; ++n)
#pragma unroll
        for (int j = 0; j < 4; ++j) {
          int r = m0 + wr * 64 + m * 16 + lqq * 4 + j;
          int cidx = n0 + wc * 64 + n * 16 + l16;
          float v = acc[m][n][j];
          if constexpr (sizeof(OutT) == 4) C[(size_t)r * N + cidx] = v;
          else C[(size_t)r * N + cidx] = f2bf(v);
        }
  }
}

// ---------------- flash attention (causal) — ROUND-2-EXACT (proven pass) ----------------
// grid: 512 blocks; each block handles q-tile pair {qp, 31-qp} for one (b,h).
__global__ __launch_bounds__(256) void attn_kernel(
    const unsigned short* __restrict__ Qg, const unsigned short* __restrict__ Kg,
    const unsigned short* __restrict__ Vtg, unsigned short* __restrict__ Og) {
  __shared__ unsigned short sQ[64 * 64];
  __shared__ unsigned short sK[64 * 64];
  __shared__ unsigned short sVt[64 * 64];      // transposed tile: [dv][kv], swizzled
  __shared__ unsigned short sP[4][16 * 64];    // per-wave P tile, swizzled
  const int tid = threadIdx.x, wave = tid >> 6, lane = tid & 63;
  const int l16 = lane & 15, lq = lane >> 4;
  const int id = blockIdx.x;
  const int bh = (id & 7) * 4 + ((id >> 3) & 3);   // XCD-grouped (b,h)
  const int qpair = id >> 5;                        // 0..15
  const int b = bh >> 4, h = bh & 15;
  const size_t tokbase = (size_t)b * S_ * D_ + h * DK_;
  const unsigned short* VtB = Vtg + (size_t)(b * H_ + h) * DK_ * S_;
  unsigned short* sPw = sP[wave];

#pragma unroll 1
  for (int side = 0; side < 2; ++side) {
    const int qt = side ? (31 - qpair) : qpair;
    const int q0 = qt * 64;

    __syncthreads();
    stage64x64_swz(Qg + tokbase + (size_t)q0 * D_, D_, sQ, wave, lane);
    __syncthreads();
    bf16x8 aq0 = rdswz(sQ, wave * 16 + l16, 0 + lq * 8);
    bf16x8 aq1 = rdswz(sQ, wave * 16 + l16, 32 + lq * 8);

    float m_run[4] = {-1e30f, -1e30f, -1e30f, -1e30f};
    float l_run[4] = {0.f, 0.f, 0.f, 0.f};
    f32x4 o_acc[4] = {};

#pragma unroll 1
    for (int kt = 0; kt <= qt; ++kt) {
      __syncthreads();   // (A) prior iteration's reads of sK/sVt complete
      stage64x64_swz(Kg + tokbase + (size_t)(kt * 64) * D_, D_, sK, wave, lane);
      stage64x64_swz(VtB + kt * 64, S_, sVt, wave, lane);
      __syncthreads();   // (B) staging drained

      // QK^T: S[16 q][64 k]
      f32x4 sc[4];
#pragma unroll
      for (int nb = 0; nb < 4; ++nb) {
        bf16x8 bk0 = rdswz(sK, nb * 16 + l16, 0 + lq * 8);
        bf16x8 bk1 = rdswz(sK, nb * 16 + l16, 32 + lq * 8);
        f32x4 a = {};
        a = __builtin_amdgcn_mfma_f32_16x16x32_bf16(aq0, bk0, a, 0, 0, 0);
        a = __builtin_amdgcn_mfma_f32_16x16x32_bf16(aq1, bk1, a, 0, 0, 0);
        sc[nb] = a;
      }

      // scale + causal mask (diagonal tile only) + online softmax
      float p[4][4];
#pragma unroll
      for (int nb = 0; nb < 4; ++nb)
#pragma unroll
        for (int j = 0; j < 4; ++j) p[nb][j] = sc[nb][j] * 0.125f;
      if (kt == qt) {
#pragma unroll
        for (int nb = 0; nb < 4; ++nb)
#pragma unroll
          for (int j = 0; j < 4; ++j) {
            int kidx = nb * 16 + l16;
            int qidx = wave * 16 + lq * 4 + j;
            if (kidx > qidx) p[nb][j] = -1e30f;
          }
      }
#pragma unroll
      for (int j = 0; j < 4; ++j) {
        float rmax = fmaxf(fmaxf(p[0][j], p[1][j]), fmaxf(p[2][j], p[3][j]));
#pragma unroll
        for (int d = 1; d < 16; d <<= 1) rmax = fmaxf(rmax, __shfl_xor(rmax, d));
        float mn = fmaxf(m_run[j], rmax);
        float alpha = __expf(m_run[j] - mn);
        m_run[j] = mn;
        const int rw = lq * 4 + j;
        float ps = 0.f;
#pragma unroll
        for (int nb = 0; nb < 4; ++nb) {
          float e = __expf(p[nb][j] - mn);
          ps += e;
          sPw[rw * 64 + ((nb * 16 + l16) ^ ((rw & 7) << 3))] = f2bf(e);
        }
#pragma unroll
        for (int d = 1; d < 16; d <<= 1) ps += __shfl_xor(ps, d);
        l_run[j] = l_run[j] * alpha + ps;
#pragma unroll
        for (int nb = 0; nb < 4; ++nb) o_acc[nb][j] *= alpha;
      }

      // PV: O[16 q][64 dv] += P[16 q][64 kv] * Vt[64 dv][64 kv]^T
#pragma unroll
      for (int kk = 0; kk < 2; ++kk) {
        bf16x8 ap = rdswz(sPw, l16, kk * 32 + lq * 8);
#pragma unroll
        for (int nb = 0; nb < 4; ++nb) {
          bf16x8 bv = rdswz(sVt, nb * 16 + l16, kk * 32 + lq * 8);
          o_acc[nb] = __builtin_amdgcn_mfma_f32_16x16x32_bf16(ap, bv, o_acc[nb], 0, 0, 0);
        }
      }
    }

    // normalize + store bf16
#pragma unroll
    for (int j = 0; j < 4; ++j) {
      float inv = 1.f / l_run[j];
#pragma unroll
      for (int nb = 0; nb < 4; ++nb) {
        int r = q0 + wave * 16 + lq * 4 + j;
        Og[tokbase + (size_t)r * D_ + nb * 16 + l16] = f2bf(o_acc[nb][j] * inv);
      }
    }
  }
}

// ---------------- launch ----------------
extern "C" void kernel_launch(void* const* d_in, const int* in_sizes, int n_in,
                              void* d_out, int out_size, void* d_ws, size_t ws_size,
                              hipStream_t stream) {
  const float* x = (const float*)d_in[0];
  const float* wq = (const float*)d_in[1];
  const float* wk = (const float*)d_in[2];
  const float* wv = (const float*)d_in[3];
  const float* wo = (const float*)d_in[4];
  float* out = (float*)d_out;

  char* ws = (char*)d_ws;
  const size_t MB = 1024 * 1024;
  unsigned short* xb  = (unsigned short*)(ws + 0);        // 8MB
  unsigned short* wqb = (unsigned short*)(ws + 8 * MB);
  unsigned short* wkb = (unsigned short*)(ws + 10 * MB);
  unsigned short* wvb = (unsigned short*)(ws + 12 * MB);
  unsigned short* wob = (unsigned short*)(ws + 14 * MB);
  unsigned short* Qb  = (unsigned short*)(ws + 16 * MB);  // 8MB
  unsigned short* Kb  = (unsigned short*)(ws + 24 * MB);  // 8MB
  unsigned short* Vtb = (unsigned short*)(ws + 32 * MB);  // 8MB, V^T written by GEMM
  unsigned short* AOb = (unsigned short*)(ws + 40 * MB);  // 8MB

  const int M = B_ * S_;
  const int N = D_, K = D_;

  cvt_kernel<<<dim3((M * D_ / 4 + 255) / 256), 256, 0, stream>>>(x, xb, M * D_ / 4);
  cvtw_kernel<<<dim3(D_ * D_ / 4 / 256, 4), 256, 0, stream>>>(wq, wk, wv, wo, wqb, wkb, wvb, wob);

  // fused QKV projection; V (mat 2) written directly transposed into Vtb
  gemm_bt<unsigned short, true><<<dim3(3 * (N / BN), M / BM), 256, 0, stream>>>(
      xb, wqb, wkb, wvb, Qb, Kb, Vtb, M, N, K);

  // causal flash attention (round-2-exact)
  attn_kernel<<<dim3(512), 256, 0, stream>>>(Qb, Kb, Vtb, AOb);

  // output projection -> fp32 d_out
  gemm_bt<float, false><<<dim3(N / BN, M / BM), 256, 0, stream>>>(
      AOb, wob, wob, wob, out, out, out, M, N, K);
}

// Round 6
// 148.212 us; speedup vs baseline: 1.8417x; 1.0308x over previous
//
#include <hip/hip_runtime.h>
#include <hip/hip_bf16.h>
#include <cstdint>

// Problem: B=2, S=2048, D=1024, H=16, DK=64. fp32 I/O, bf16 MFMA compute.
#define B_ 2
#define S_ 2048
#define D_ 1024
#define H_ 16
#define DK_ 64

typedef __attribute__((ext_vector_type(8))) short bf16x8;
typedef __attribute__((ext_vector_type(4))) float f32x4;

__device__ __forceinline__ unsigned short f2bf(float f) {
  unsigned u = __float_as_uint(f);
  u = (u + 0x7FFFu + ((u >> 16) & 1u)) >> 16;
  return (unsigned short)u;
}

typedef __attribute__((address_space(1))) void gv_t;
typedef __attribute__((address_space(3))) void lv_t;
__device__ __forceinline__ void gl16(const void* g, void* l) {
  __builtin_amdgcn_global_load_lds((gv_t*)g, (lv_t*)l, 16, 0, 0);
}

// Stage a 64x64 bf16 tile into LDS (linear dest) with inverse-swizzled global
// source: LDS slot (row, g16) holds global group g16 ^ (row&7).  (T21)
// 4-wave version (GEMM blocks).
__device__ __forceinline__ void stage64x64_swz(const unsigned short* gbase, size_t ldg,
                                               unsigned short* lds, int wave, int lane) {
  const int lr = lane >> 3;
  const int col8 = (lane & 7) ^ lr;
#pragma unroll
  for (int q = 0; q < 4; ++q) {
    int c = q * 4 + wave;
    int row = c * 8 + lr;
    gl16(gbase + (size_t)row * ldg + col8 * 8, lds + c * 512);
  }
}

// 8-wave version (attn blocks): wave w stages chunks {w, 8+w}.
__device__ __forceinline__ void stage64x64_swz8(const unsigned short* gbase, size_t ldg,
                                                unsigned short* lds, int wave, int lane) {
  const int lr = lane >> 3;
  const int col8 = (lane & 7) ^ lr;
#pragma unroll
  for (int q = 0; q < 2; ++q) {
    int c = q * 8 + wave;
    int row = c * 8 + lr;
    gl16(gbase + (size_t)row * ldg + col8 * 8, lds + c * 512);
  }
}

__device__ __forceinline__ bf16x8 rdswz(const unsigned short* lds, int row, int colelem) {
  return *(const bf16x8*)&lds[row * 64 + (colelem ^ ((row & 7) << 3))];
}

// ---------------- fp32 -> bf16 converts ----------------
__global__ void cvt_kernel(const float* __restrict__ in, unsigned short* __restrict__ out, int n4) {
  int i = blockIdx.x * blockDim.x + threadIdx.x;
  if (i >= n4) return;
  const float4 v = reinterpret_cast<const float4*>(in)[i];
  ushort4 o;
  o.x = f2bf(v.x); o.y = f2bf(v.y); o.z = f2bf(v.z); o.w = f2bf(v.w);
  reinterpret_cast<ushort4*>(out)[i] = o;
}

__global__ void cvtw_kernel(const float* __restrict__ w0, const float* __restrict__ w1,
                            const float* __restrict__ w2, const float* __restrict__ w3,
                            unsigned short* __restrict__ o0, unsigned short* __restrict__ o1,
                            unsigned short* __restrict__ o2, unsigned short* __restrict__ o3) {
  const int mat = blockIdx.y;
  const float* in = (mat == 0) ? w0 : (mat == 1) ? w1 : (mat == 2) ? w2 : w3;
  unsigned short* out = (mat == 0) ? o0 : (mat == 1) ? o1 : (mat == 2) ? o2 : o3;
  int i = blockIdx.x * blockDim.x + threadIdx.x;
  const float4 v = reinterpret_cast<const float4*>(in)[i];
  ushort4 o;
  o.x = f2bf(v.x); o.y = f2bf(v.y); o.z = f2bf(v.z); o.w = f2bf(v.w);
  reinterpret_cast<ushort4*>(out)[i] = o;
}

// ---------------- GEMM: C = A * B^T ----------------
// TV2: matrix index 2 writes its output TRANSPOSED into Vt[((b*H+h)*DK+dv)*S+s]
#define BM 128
#define BN 128
#define BK 64

template <typename OutT, bool TV2>
__global__ __launch_bounds__(256) void gemm_bt(
    const unsigned short* __restrict__ A,
    const unsigned short* __restrict__ B0, const unsigned short* __restrict__ B1,
    const unsigned short* __restrict__ B2,
    OutT* __restrict__ C0, OutT* __restrict__ C1, OutT* __restrict__ C2,
    int M, int N, int K) {
  __shared__ unsigned short lA[BM * BK];
  __shared__ unsigned short lB[BN * BK];
  const int tid = threadIdx.x;
  const int wave = tid >> 6, lane = tid & 63;
  const int l16 = lane & 15, lqq = lane >> 4;
  const int wr = wave >> 1, wc = wave & 1;
  const int lr = lane >> 3;
  const int col8 = ((lane & 7) ^ lr) * 8;

  const int tilesPerMat = N / BN;
  const int bx = blockIdx.x;
  const int mat = bx / tilesPerMat;
  const int n0 = (bx % tilesPerMat) * BN;
  const unsigned short* Bm = (mat == 0) ? B0 : (mat == 1) ? B1 : B2;
  OutT* C = (mat == 0) ? C0 : (mat == 1) ? C1 : C2;
  const int m0 = blockIdx.y * BM;

  f32x4 acc[4][4] = {};

  for (int k0 = 0; k0 < K; k0 += BK) {
    __syncthreads();
#pragma unroll
    for (int q = 0; q < 4; ++q) {
      int c = q * 4 + wave;
      int row = c * 8 + lr;
      gl16(A + (size_t)(m0 + row) * K + k0 + col8, &lA[c * 512]);
      gl16(Bm + (size_t)(n0 + row) * K + k0 + col8, &lB[c * 512]);
    }
    __syncthreads();
#pragma unroll
    for (int kk = 0; kk < BK / 32; ++kk) {
      bf16x8 af[4], bfr[4];
#pragma unroll
      for (int m = 0; m < 4; ++m)
        af[m] = rdswz(lA, wr * 64 + m * 16 + l16, kk * 32 + lqq * 8);
#pragma unroll
      for (int n = 0; n < 4; ++n)
        bfr[n] = rdswz(lB, wc * 64 + n * 16 + l16, kk * 32 + lqq * 8);
      __builtin_amdgcn_s_setprio(1);
#pragma unroll
      for (int m = 0; m < 4; ++m)
#pragma unroll
        for (int n = 0; n < 4; ++n)
          acc[m][n] = __builtin_amdgcn_mfma_f32_16x16x32_bf16(af[m], bfr[n], acc[m][n], 0, 0, 0);
      __builtin_amdgcn_s_setprio(0);
    }
  }

  if (TV2 && mat == 2) {
    unsigned short* Vt = (unsigned short*)C;
#pragma unroll
    for (int m = 0; m < 4; ++m)
#pragma unroll
      for (int n = 0; n < 4; ++n) {
        int r0 = m0 + wr * 64 + m * 16 + lqq * 4;
        int cidx = n0 + wc * 64 + n * 16 + l16;
        int bb = r0 >> 11, s = r0 & 2047;
        int h = cidx >> 6, dv = cidx & 63;
        ushort4 o;
        o.x = f2bf(acc[m][n][0]); o.y = f2bf(acc[m][n][1]);
        o.z = f2bf(acc[m][n][2]); o.w = f2bf(acc[m][n][3]);
        *(ushort4*)(Vt + ((size_t)((bb * H_ + h) * DK_ + dv)) * S_ + s) = o;
      }
  } else {
#pragma unroll
    for (int m = 0; m < 4; ++m)
#pragma unroll
      for (int n = 0; n < 4; ++n)
#pragma unroll
        for (int j = 0; j < 4; ++j) {
          int r = m0 + wr * 64 + m * 16 + lqq * 4 + j;
          int cidx = n0 + wc * 64 + n * 16 + l16;
          float v = acc[m][n][j];
          if constexpr (sizeof(OutT) == 4) C[(size_t)r * N + cidx] = v;
          else C[(size_t)r * N + cidx] = f2bf(v);
        }
  }
}

// ---------------- flash attention (causal) ----------------
// 512-thread blocks: waves 0-3 compute q-tile qtA, waves 4-7 compute q-tile
// qtB = 31-qtA, SHARING one K/V staging stream.  Per-iteration sync pattern
// and softmax math are byte-identical to the proven round-2 kernel; the only
// change is the wave split (compute guarded, barriers uniform).
__global__ __launch_bounds__(512) void attn_kernel(
    const unsigned short* __restrict__ Qg, const unsigned short* __restrict__ Kg,
    const unsigned short* __restrict__ Vtg, unsigned short* __restrict__ Og) {
  __shared__ unsigned short sQ[2][64 * 64];
  __shared__ unsigned short sK[64 * 64];
  __shared__ unsigned short sVt[64 * 64];      // transposed tile: [dv][kv], swizzled
  __shared__ unsigned short sP[8][16 * 64];    // per-wave P tile, swizzled
  const int tid = threadIdx.x, wave = tid >> 6, lane = tid & 63;
  const int side = wave >> 2, wq = wave & 3;
  const int l16 = lane & 15, lq = lane >> 4;
  const int id = blockIdx.x;
  const int bh = (id & 7) * 4 + ((id >> 3) & 3);   // XCD-grouped (b,h)
  const int qpair = id >> 5;                        // 0..15
  const int b = bh >> 4, h = bh & 15;
  const int qtA = qpair, qtB = 31 - qpair;
  const int qt_s = side ? qtB : qtA;                // this wave's q-tile
  const size_t tokbase = (size_t)b * S_ * D_ + h * DK_;
  const unsigned short* VtB = Vtg + (size_t)(b * H_ + h) * DK_ * S_;
  unsigned short* sPw = sP[wave];

  // prologue: stage both Q tiles (8-wave split each)
  stage64x64_swz8(Qg + tokbase + (size_t)(qtA * 64) * D_, D_, sQ[0], wave, lane);
  stage64x64_swz8(Qg + tokbase + (size_t)(qtB * 64) * D_, D_, sQ[1], wave, lane);
  __syncthreads();
  bf16x8 aq0 = rdswz(sQ[side], wq * 16 + l16, 0 + lq * 8);
  bf16x8 aq1 = rdswz(sQ[side], wq * 16 + l16, 32 + lq * 8);

  float m_run[4] = {-1e30f, -1e30f, -1e30f, -1e30f};
  float l_run[4] = {0.f, 0.f, 0.f, 0.f};
  f32x4 o_acc[4] = {};

#pragma unroll 1
  for (int kt = 0; kt <= qtB; ++kt) {
    __syncthreads();   // (A) prior iteration's reads of sK/sVt complete
    stage64x64_swz8(Kg + tokbase + (size_t)(kt * 64) * D_, D_, sK, wave, lane);
    stage64x64_swz8(VtB + kt * 64, S_, sVt, wave, lane);
    __syncthreads();   // (B) staging drained

    if (side || kt <= qtA) {
      // QK^T: S[16 q][64 k]
      f32x4 sc[4];
#pragma unroll
      for (int nb = 0; nb < 4; ++nb) {
        bf16x8 bk0 = rdswz(sK, nb * 16 + l16, 0 + lq * 8);
        bf16x8 bk1 = rdswz(sK, nb * 16 + l16, 32 + lq * 8);
        f32x4 a = {};
        a = __builtin_amdgcn_mfma_f32_16x16x32_bf16(aq0, bk0, a, 0, 0, 0);
        a = __builtin_amdgcn_mfma_f32_16x16x32_bf16(aq1, bk1, a, 0, 0, 0);
        sc[nb] = a;
      }

      // scale + causal mask (diagonal tile only) + online softmax
      float p[4][4];
#pragma unroll
      for (int nb = 0; nb < 4; ++nb)
#pragma unroll
        for (int j = 0; j < 4; ++j) p[nb][j] = sc[nb][j] * 0.125f;
      if (kt == qt_s) {
#pragma unroll
        for (int nb = 0; nb < 4; ++nb)
#pragma unroll
          for (int j = 0; j < 4; ++j) {
            int kidx = nb * 16 + l16;
            int qidx = wq * 16 + lq * 4 + j;
            if (kidx > qidx) p[nb][j] = -1e30f;
          }
      }
#pragma unroll
      for (int j = 0; j < 4; ++j) {
        float rmax = fmaxf(fmaxf(p[0][j], p[1][j]), fmaxf(p[2][j], p[3][j]));
#pragma unroll
        for (int d = 1; d < 16; d <<= 1) rmax = fmaxf(rmax, __shfl_xor(rmax, d));
        float mn = fmaxf(m_run[j], rmax);
        float alpha = __expf(m_run[j] - mn);
        m_run[j] = mn;
        const int rw = lq * 4 + j;
        float ps = 0.f;
#pragma unroll
        for (int nb = 0; nb < 4; ++nb) {
          float e = __expf(p[nb][j] - mn);
          ps += e;
          sPw[rw * 64 + ((nb * 16 + l16) ^ ((rw & 7) << 3))] = f2bf(e);
        }
#pragma unroll
        for (int d = 1; d < 16; d <<= 1) ps += __shfl_xor(ps, d);
        l_run[j] = l_run[j] * alpha + ps;
#pragma unroll
        for (int nb = 0; nb < 4; ++nb) o_acc[nb][j] *= alpha;
      }

      // PV: O[16 q][64 dv] += P[16 q][64 kv] * Vt[64 dv][64 kv]^T
#pragma unroll
      for (int kk = 0; kk < 2; ++kk) {
        bf16x8 ap = rdswz(sPw, l16, kk * 32 + lq * 8);
#pragma unroll
        for (int nb = 0; nb < 4; ++nb) {
          bf16x8 bv = rdswz(sVt, nb * 16 + l16, kk * 32 + lq * 8);
          o_acc[nb] = __builtin_amdgcn_mfma_f32_16x16x32_bf16(ap, bv, o_acc[nb], 0, 0, 0);
        }
      }
    }
  }

  // normalize + store bf16
#pragma unroll
  for (int j = 0; j < 4; ++j) {
    float inv = 1.f / l_run[j];
#pragma unroll
    for (int nb = 0; nb < 4; ++nb) {
      int r = qt_s * 64 + wq * 16 + lq * 4 + j;
      Og[tokbase + (size_t)r * D_ + nb * 16 + l16] = f2bf(o_acc[nb][j] * inv);
    }
  }
}

// ---------------- launch ----------------
extern "C" void kernel_launch(void* const* d_in, const int* in_sizes, int n_in,
                              void* d_out, int out_size, void* d_ws, size_t ws_size,
                              hipStream_t stream) {
  const float* x = (const float*)d_in[0];
  const float* wq = (const float*)d_in[1];
  const float* wk = (const float*)d_in[2];
  const float* wv = (const float*)d_in[3];
  const float* wo = (const float*)d_in[4];
  float* out = (float*)d_out;

  char* ws = (char*)d_ws;
  const size_t MB = 1024 * 1024;
  unsigned short* xb  = (unsigned short*)(ws + 0);        // 8MB
  unsigned short* wqb = (unsigned short*)(ws + 8 * MB);
  unsigned short* wkb = (unsigned short*)(ws + 10 * MB);
  unsigned short* wvb = (unsigned short*)(ws + 12 * MB);
  unsigned short* wob = (unsigned short*)(ws + 14 * MB);
  unsigned short* Qb  = (unsigned short*)(ws + 16 * MB);  // 8MB
  unsigned short* Kb  = (unsigned short*)(ws + 24 * MB);  // 8MB
  unsigned short* Vtb = (unsigned short*)(ws + 32 * MB);  // 8MB, V^T written by GEMM
  unsigned short* AOb = (unsigned short*)(ws + 40 * MB);  // 8MB

  const int M = B_ * S_;
  const int N = D_, K = D_;

  cvt_kernel<<<dim3((M * D_ / 4 + 255) / 256), 256, 0, stream>>>(x, xb, M * D_ / 4);
  cvtw_kernel<<<dim3(D_ * D_ / 4 / 256, 4), 256, 0, stream>>>(wq, wk, wv, wo, wqb, wkb, wvb, wob);

  // fused QKV projection; V (mat 2) written directly transposed into Vtb
  gemm_bt<unsigned short, true><<<dim3(3 * (N / BN), M / BM), 256, 0, stream>>>(
      xb, wqb, wkb, wvb, Qb, Kb, Vtb, M, N, K);

  // causal flash attention (8-wave blocks, shared KV stream per q-pair)
  attn_kernel<<<dim3(512), 512, 0, stream>>>(Qb, Kb, Vtb, AOb);

  // output projection -> fp32 d_out
  gemm_bt<float, false><<<dim3(N / BN, M / BM), 256, 0, stream>>>(
      AOb, wob, wob, wob, out, out, out, M, N, K);
}